// Round 1
// baseline (25.520 us; speedup 1.0000x reference)
//
#include <hip/hip_runtime.h>

// Rank IGR Loss — factorized pair-sum implementation.
//
// Reference math per batch b:
//   prob[n] = exp(cls[b,n,1]);  pos[n] = label_cls[b,n] > 0
//   iou[n]  = IoU(pred_bboxes[b,:,n], label_target[b,:])   (in [0,1])
//   d[n]    = || (loc[b,0,n]+tx1, loc[b,1,n]+ty1) - (tcx,tcy) ||
//   pair[i,j] = pos[i] & pos[j] & (d[j]-d[i] >= 1)
//   l1 = sum_pairs exp(-G1*(p_i-p_j)) / max(cnt,1)
//   l2 = sum_pairs exp(-G2*(iou_i-iou_j)) / max(cnt,1)
//   f1,f2 = masked batch means (valid = dataset_id!=1 && cnt>0)
//
// Factorization: exp(-G*(a_i-a_j)) = exp(-G*a_i)*exp(G*a_j); the pair loop
// then needs only d-compare + conditional adds.

#define G1 3.0f
#define G2 1.0f

constexpr int B = 16;
constexpr int N = 2048;
constexpr int TILE = 256;
constexpr int ICH = N / TILE;   // 8 i-chunks
constexpr int JCH = N / TILE;   // 8 j-chunks
constexpr int PB  = ICH * JCH;  // 64 partial sets per batch

// ws layout:
//   [0, 32768)                     : double part[B*PB*3]   (24 KB used)
//   [32768, +B*N*16)               : float4 jd[B*N]  = {d, w1, w2, posf}
//   then                           : float v1[B*N], v2[B*N]
constexpr size_t PART_BYTES = 32768;

__global__ void precompute_kernel(const float* __restrict__ cls,
                                  const int*   __restrict__ label_cls,
                                  const float* __restrict__ label_loc,
                                  const float* __restrict__ pred,
                                  const float* __restrict__ tgt,
                                  float4* __restrict__ jd,
                                  float*  __restrict__ v1,
                                  float*  __restrict__ v2) {
  int idx = blockIdx.x * blockDim.x + threadIdx.x;  // = b*N + n
  if (idx >= B * N) return;
  int b = idx >> 11;          // / N
  int n = idx & (N - 1);

  float tx1 = tgt[b * 4 + 0], ty1 = tgt[b * 4 + 1];
  float tx2 = tgt[b * 4 + 2], ty2 = tgt[b * 4 + 3];

  const float* pb = pred + (size_t)b * 4 * N;
  float x1 = pb[n], y1 = pb[N + n], x2 = pb[2 * N + n], y2 = pb[3 * N + n];
  float ww = fmaxf(fminf(tx2, x2) - fmaxf(tx1, x1), 0.f);
  float hh = fmaxf(fminf(ty2, y2) - fmaxf(ty1, y1), 0.f);
  float area  = (x2 - x1) * (y2 - y1);
  float ta    = (tx2 - tx1) * (ty2 - ty1);
  float inter = ww * hh;
  float iou   = inter / (area + ta - inter);

  float prob = expf(cls[(size_t)idx * 2 + 1]);
  bool  pos  = label_cls[idx] > 0;

  const float* lb = label_loc + (size_t)b * 4 * N;
  float cx = lb[n] + tx1;
  float cy = lb[N + n] + ty1;
  float tcx = (tx1 + tx2) * 0.5f, tcy = (ty1 + ty2) * 0.5f;
  float dx = cx - tcx, dy = cy - tcy;
  float d  = sqrtf(dx * dx + dy * dy);

  float w1 = pos ? expf(G1 * prob) : 0.f;
  float w2 = pos ? expf(G2 * iou)  : 0.f;
  jd[idx] = make_float4(d, w1, w2, pos ? 1.f : 0.f);
  v1[idx] = pos ? expf(-G1 * prob) : 0.f;
  v2[idx] = pos ? expf(-G2 * iou)  : 0.f;
}

__global__ void __launch_bounds__(256)
pair_kernel(const float4* __restrict__ jd,
            const float*  __restrict__ v1,
            const float*  __restrict__ v2,
            double* __restrict__ part) {
  __shared__ float4 sj[TILE];
  __shared__ double red[3][4];

  int bid = blockIdx.x;
  int b   = bid / PB;
  int r   = bid % PB;
  int ic  = r / JCH, jc = r % JCH;
  int t   = threadIdx.x;
  int base = b * N;
  int i    = ic * TILE + t;

  sj[t] = jd[base + jc * TILE + t];
  float4 me  = jd[base + i];
  float  di  = me.x;
  float  posi = me.w;
  float  v1i = v1[base + i];
  float  v2i = v2[base + i];
  __syncthreads();

  float s1 = 0.f, s2 = 0.f, sc = 0.f;
#pragma unroll 8
  for (int q = 0; q < TILE; ++q) {
    float4 j4 = sj[q];                 // LDS broadcast (same addr all lanes)
    bool ok = (j4.x - di >= 1.0f);     // d[j] - d[i] >= 1
    s1 += ok ? j4.y : 0.f;             // w1[j] already 0 if !pos[j]
    s2 += ok ? j4.z : 0.f;
    sc += ok ? j4.w : 0.f;             // counts pos[j] only
  }

  double p1 = (double)v1i * (double)s1;   // v1i==0 if !pos[i]
  double p2 = (double)v2i * (double)s2;
  double pc = (double)posi * (double)sc;

  for (int off = 32; off; off >>= 1) {
    p1 += __shfl_down(p1, off);
    p2 += __shfl_down(p2, off);
    pc += __shfl_down(pc, off);
  }
  int wave = t >> 6, lane = t & 63;
  if (lane == 0) { red[0][wave] = p1; red[1][wave] = p2; red[2][wave] = pc; }
  __syncthreads();
  if (t == 0) {
    double a = 0, bb = 0, c = 0;
    for (int wv = 0; wv < 4; ++wv) { a += red[0][wv]; bb += red[1][wv]; c += red[2][wv]; }
    part[(size_t)bid * 3 + 0] = a;
    part[(size_t)bid * 3 + 1] = bb;
    part[(size_t)bid * 3 + 2] = c;
  }
}

__global__ void finalize_kernel(const double* __restrict__ part,
                                const int* __restrict__ dataset_id,
                                float* __restrict__ out) {
  __shared__ double sl1[B], sl2[B], sv[B];
  int t = threadIdx.x;
  int b = t >> 4, k = t & 15;

  double s1 = 0, s2 = 0, sc = 0;
  for (int q = 0; q < PB; q += 16) {
    size_t idx = (size_t)(b * PB + k + q) * 3;
    s1 += part[idx]; s2 += part[idx + 1]; sc += part[idx + 2];
  }
  for (int off = 8; off; off >>= 1) {
    s1 += __shfl_down(s1, off, 16);
    s2 += __shfl_down(s2, off, 16);
    sc += __shfl_down(sc, off, 16);
  }
  if (k == 0) {
    double denom = fmax(sc, 1.0);
    bool valid = (dataset_id[b] != 1) && (sc > 0.0);
    sl1[b] = valid ? s1 / denom : 0.0;
    sl2[b] = valid ? s2 / denom : 0.0;
    sv[b]  = valid ? 1.0 : 0.0;
  }
  __syncthreads();
  if (t == 0) {
    double nv = 0, f1 = 0, f2 = 0;
    for (int bb = 0; bb < B; ++bb) { nv += sv[bb]; f1 += sl1[bb]; f2 += sl2[bb]; }
    if (nv > 0) { f1 /= nv; f2 /= nv; } else { f1 = 0; f2 = 0; }
    out[0] = (float)f1;
    out[1] = (float)f2;
  }
}

extern "C" void kernel_launch(void* const* d_in, const int* in_sizes, int n_in,
                              void* d_out, int out_size, void* d_ws, size_t ws_size,
                              hipStream_t stream) {
  const float* cls       = (const float*)d_in[0];
  const int*   label_cls = (const int*)d_in[1];
  const float* label_loc = (const float*)d_in[2];
  const float* pred      = (const float*)d_in[3];
  const float* tgt       = (const float*)d_in[4];
  const int*   dset      = (const int*)d_in[5];

  char*   ws   = (char*)d_ws;
  double* part = (double*)ws;
  float4* jd   = (float4*)(ws + PART_BYTES);
  float*  v1   = (float*)(ws + PART_BYTES + (size_t)B * N * sizeof(float4));
  float*  v2   = v1 + (size_t)B * N;

  precompute_kernel<<<(B * N) / 256, 256, 0, stream>>>(cls, label_cls, label_loc,
                                                       pred, tgt, jd, v1, v2);
  pair_kernel<<<B * PB, 256, 0, stream>>>(jd, v1, v2, part);
  finalize_kernel<<<1, 256, 0, stream>>>(part, dset, (float*)d_out);
}

// Round 2
// 19.524 us; speedup vs baseline: 1.3071x; 1.3071x over previous
//
#include <hip/hip_runtime.h>

// Rank IGR Loss — fused precompute + factorized pair-sum.
//
//   pair[i,j] = pos[i] & pos[j] & (d[j]-d[i] >= 1)
//   l1 = sum_pairs exp(-G1*(p_i-p_j)) / max(cnt,1)  ; factorized as
//        exp(-G1*p_i) * exp(G1*p_j)
//   l2 likewise with iou. pos[j] is folded into d'[j] = pos ? d : -1e30 so
//   the inner loop is: sub, cmp, cndmask(f), fma, fma, add  (6 VALU/pair),
//   with one broadcast ds_read_b128 amortized over IPT=4 i-values.

#define G1 3.0f
#define G2 1.0f

constexpr int B = 16;
constexpr int N = 2048;
constexpr int TI  = 1024;          // i-tile per block (256 thr * IPT)
constexpr int TJ  = 64;            // j-tile per block
constexpr int IPT = 4;             // i per thread
constexpr int ICH = N / TI;        // 2
constexpr int JCH = N / TJ;        // 32
constexpr int PB  = ICH * JCH;     // 64 partial-triples per batch
constexpr int NBLK = B * PB;       // 1024 blocks

__global__ void __launch_bounds__(256)
fused_pair_kernel(const float* __restrict__ cls,
                  const int*   __restrict__ label_cls,
                  const float* __restrict__ label_loc,
                  const float* __restrict__ pred,
                  const float* __restrict__ tgt,
                  double* __restrict__ part) {
  __shared__ float4 sj[TJ];
  __shared__ double red[3][4];

  const int bid = blockIdx.x;
  const int b   = bid >> 6;        // / PB
  const int r   = bid & 63;
  const int ic  = r >> 5;          // / JCH
  const int jc  = r & 31;
  const int t   = threadIdx.x;
  const int base = b * N;

  // target box (uniform per block -> scalar loads)
  const float tx1 = tgt[b * 4 + 0], ty1 = tgt[b * 4 + 1];
  const float tx2 = tgt[b * 4 + 2], ty2 = tgt[b * 4 + 3];
  const float ta  = (tx2 - tx1) * (ty2 - ty1);
  const float tcx = (tx1 + tx2) * 0.5f, tcy = (ty1 + ty2) * 0.5f;

  const float* __restrict__ pb = pred      + (size_t)b * 4 * N;
  const float* __restrict__ lb = label_loc + (size_t)b * 4 * N;

  auto elem = [&](int n, float& d, float& prob, float& iou, bool& pos) {
    float x1 = pb[n], y1 = pb[N + n], x2 = pb[2 * N + n], y2 = pb[3 * N + n];
    float ww = fmaxf(fminf(tx2, x2) - fmaxf(tx1, x1), 0.f);
    float hh = fmaxf(fminf(ty2, y2) - fmaxf(ty1, y1), 0.f);
    float inter = ww * hh;
    iou  = inter / ((x2 - x1) * (y2 - y1) + ta - inter);
    prob = __expf(cls[((size_t)(base + n)) * 2 + 1]);
    pos  = label_cls[base + n] > 0;
    float cx = lb[n] + tx1, cy = lb[N + n] + ty1;
    float dx = cx - tcx, dy = cy - tcy;
    d = sqrtf(dx * dx + dy * dy);
  };

  // ---- stage j tile (wave 0 only) ----
  if (t < TJ) {
    float d, prob, iou; bool pos;
    elem(jc * TJ + t, d, prob, iou, pos);
    sj[t] = make_float4(pos ? d : -1e30f,       // !pos[j] can never satisfy >= 1
                        __expf(G1 * prob),
                        __expf(G2 * iou), 0.f);
  }

  // ---- per-thread i data (4 coalesced strips) ----
  float di[IPT], v1i[IPT], v2i[IPT], posi[IPT];
#pragma unroll
  for (int k = 0; k < IPT; ++k) {
    float d, prob, iou; bool pos;
    elem(ic * TI + k * 256 + t, d, prob, iou, pos);
    di[k]   = d;
    posi[k] = pos ? 1.f : 0.f;
    v1i[k]  = pos ? __expf(-G1 * prob) : 0.f;
    v2i[k]  = pos ? __expf(-G2 * iou)  : 0.f;
  }
  __syncthreads();

  // ---- pair loop: 1 broadcast ds_read_b128 feeds IPT pairs ----
  float s1[IPT] = {}, s2[IPT] = {}, sc[IPT] = {};
#pragma unroll 8
  for (int q = 0; q < TJ; ++q) {
    const float4 j4 = sj[q];
#pragma unroll
    for (int k = 0; k < IPT; ++k) {
      // keep exact reference rounding: d[j] - d[i] >= 1.0
      float f = (j4.x - di[k] >= 1.0f) ? 1.0f : 0.0f;
      s1[k] = fmaf(f, j4.y, s1[k]);
      s2[k] = fmaf(f, j4.z, s2[k]);
      sc[k] += f;
    }
  }

  double p1 = 0, p2 = 0, pc = 0;
#pragma unroll
  for (int k = 0; k < IPT; ++k) {
    p1 += (double)v1i[k]  * (double)s1[k];
    p2 += (double)v2i[k]  * (double)s2[k];
    pc += (double)posi[k] * (double)sc[k];
  }

  for (int off = 32; off; off >>= 1) {
    p1 += __shfl_down(p1, off);
    p2 += __shfl_down(p2, off);
    pc += __shfl_down(pc, off);
  }
  const int wave = t >> 6, lane = t & 63;
  if (lane == 0) { red[0][wave] = p1; red[1][wave] = p2; red[2][wave] = pc; }
  __syncthreads();
  if (t == 0) {
    double a = 0, bb = 0, c = 0;
    for (int wv = 0; wv < 4; ++wv) { a += red[0][wv]; bb += red[1][wv]; c += red[2][wv]; }
    part[(size_t)bid * 3 + 0] = a;
    part[(size_t)bid * 3 + 1] = bb;
    part[(size_t)bid * 3 + 2] = c;
  }
}

__global__ void finalize_kernel(const double* __restrict__ part,
                                const int* __restrict__ dataset_id,
                                float* __restrict__ out) {
  __shared__ double sl1[B], sl2[B], sv[B];
  int t = threadIdx.x;
  int b = t >> 4, k = t & 15;

  double s1 = 0, s2 = 0, sc = 0;
  for (int q = 0; q < PB; q += 16) {
    size_t idx = (size_t)(b * PB + k + q) * 3;
    s1 += part[idx]; s2 += part[idx + 1]; sc += part[idx + 2];
  }
  for (int off = 8; off; off >>= 1) {
    s1 += __shfl_down(s1, off, 16);
    s2 += __shfl_down(s2, off, 16);
    sc += __shfl_down(sc, off, 16);
  }
  if (k == 0) {
    double denom = fmax(sc, 1.0);
    bool valid = (dataset_id[b] != 1) && (sc > 0.0);
    sl1[b] = valid ? s1 / denom : 0.0;
    sl2[b] = valid ? s2 / denom : 0.0;
    sv[b]  = valid ? 1.0 : 0.0;
  }
  __syncthreads();
  if (t == 0) {
    double nv = 0, f1 = 0, f2 = 0;
    for (int bb = 0; bb < B; ++bb) { nv += sv[bb]; f1 += sl1[bb]; f2 += sl2[bb]; }
    if (nv > 0) { f1 /= nv; f2 /= nv; } else { f1 = 0; f2 = 0; }
    out[0] = (float)f1;
    out[1] = (float)f2;
  }
}

extern "C" void kernel_launch(void* const* d_in, const int* in_sizes, int n_in,
                              void* d_out, int out_size, void* d_ws, size_t ws_size,
                              hipStream_t stream) {
  const float* cls       = (const float*)d_in[0];
  const int*   label_cls = (const int*)d_in[1];
  const float* label_loc = (const float*)d_in[2];
  const float* pred      = (const float*)d_in[3];
  const float* tgt       = (const float*)d_in[4];
  const int*   dset      = (const int*)d_in[5];

  double* part = (double*)d_ws;   // NBLK*3 doubles = 24 KB

  fused_pair_kernel<<<NBLK, 256, 0, stream>>>(cls, label_cls, label_loc,
                                              pred, tgt, part);
  finalize_kernel<<<1, 256, 0, stream>>>(part, dset, (float*)d_out);
}